// Round 11
// baseline (841.569 us; speedup 1.0000x reference)
//
#include <hip/hip_runtime.h>
#include <hip/hip_fp16.h>

#define NN 50000
#define EE 1000000
#define NHALF 25000
#define EPT 4

typedef _Float16 h8v __attribute__((ext_vector_type(8)));
typedef float    f4a __attribute__((ext_vector_type(4)));
typedef float    f4v __attribute__((ext_vector_type(4)));

__device__ __forceinline__ float wsum(float v){
#pragma unroll
  for(int m=1;m<64;m<<=1) v += __shfl_xor(v,m,64);
  return v;
}
__device__ __forceinline__ unsigned encf(float f){
  unsigned u = __float_as_uint(f);
  return (u & 0x80000000u) ? ~u : (u | 0x80000000u);
}
__device__ __forceinline__ float decf(unsigned u){
  u = (u & 0x80000000u) ? (u & 0x7fffffffu) : ~u;
  return __uint_as_float(u);
}

// prep: zero counts/cursor/mx (all blocks) + cvec + fp16 W/O transpose (blocks 0..7)
__global__ __launch_bounds__(256) void prep_k(int* counts, int* cursor, unsigned* mx,
                                              const float* __restrict__ gat_W, const float* __restrict__ gat_a,
                                              const float* __restrict__ out_W, const float* __restrict__ out_a,
                                              float* __restrict__ cdir, __half* __restrict__ WT,
                                              __half* __restrict__ OT){
  int i = blockIdx.x*256 + threadIdx.x;
  if(i < NN){ counts[i] = 0; cursor[i] = 0; }
  if(i < 64) mx[i] = 0u;
  if(blockIdx.x < 8){
    int h = blockIdx.x, tid = threadIdx.x;
    if(tid < 64){
      const float* W = gat_W + (size_t)h*4096;
      const float* a = gat_a + (size_t)h*192;
      float cs = 0.f, ct = 0.f;
#pragma unroll
      for(int j=0;j<64;j++){ float wv = W[tid*64+j]; cs += wv*a[j]; ct += wv*a[64+j]; }
      cdir[h*64 + tid]       = cs;
      cdir[512 + h*64 + tid] = ct;
    }
    for(int idx = tid; idx < 4096; idx += 256){
      int j = idx >> 6, k = idx & 63;
      WT[(size_t)h*4096 + k*64 + j] = __float2half(gat_W[(size_t)h*4096 + j*64 + k]);
      OT[(size_t)h*4096 + k*64 + j] = __float2half(out_W[(size_t)h*4096 + j*64 + k]);
    }
  }
}

// node MLP (blocks < NB_N) + edge histogram (remaining blocks)
__global__ __launch_bounds__(256) void node_hist_k(const float* __restrict__ X, const float* __restrict__ w,
                                                   const float* __restrict__ b, const float* __restrict__ g,
                                                   const float* __restrict__ beta, const float* __restrict__ cdir,
                                                   __half* __restrict__ x, float* __restrict__ ps8,
                                                   float* __restrict__ pt8,
                                                   const int* __restrict__ src, int* __restrict__ counts){
  const int NB_N = (NN*64 + 255)/256;
  if(blockIdx.x >= NB_N){
    int e = (blockIdx.x - NB_N)*256 + threadIdx.x;
    if(e < EE){
      int s = src[e];
      if((unsigned)s >= NN) s = 0;
      atomicAdd(&counts[s], 1);
    }
    return;
  }
  int wid  = (blockIdx.x*256 + threadIdx.x) >> 6;
  int lane = threadIdx.x & 63;
  if(wid >= NN) return;
  float acc = b[lane];
#pragma unroll
  for(int k=0;k<16;k++) acc += X[wid*16+k] * w[k*64+lane];
  float mu  = wsum(acc) * (1.0f/64.0f);
  float d   = acc - mu;
  float var = wsum(d*d) * (1.0f/64.0f);
  float y   = d * rsqrtf(var + 1e-5f) * g[lane] + beta[lane];
  float xv  = fmaxf(y, 0.0f);
  x[(size_t)wid*64 + lane] = __float2half(xv);
#pragma unroll 1
  for(int h=0;h<8;h++){
    float a = wsum(xv * cdir[h*64+lane]);
    float c = wsum(xv * cdir[512 + h*64+lane]);
    if(lane == 0){ ps8[wid*8+h] = a; pt8[wid*8+h] = c; }
  }
}

// single-block exclusive scan of counts -> offs
#define SCH 49   // ceil(50000/1024)
__global__ __launch_bounds__(1024) void scan_k(const int* __restrict__ counts, int* __restrict__ offs){
  __shared__ int sm[1024];
  int t = threadIdx.x;
  int base = t*SCH;
  int loc[SCH];
  int sum = 0;
#pragma unroll
  for(int i=0;i<SCH;i++){
    int idx = base+i;
    int v = (idx < NN) ? counts[idx] : 0;
    loc[i] = sum; sum += v;
  }
  sm[t] = sum; __syncthreads();
  for(int off=1; off<1024; off<<=1){
    int u = (t >= off) ? sm[t-off] : 0;
    __syncthreads();
    sm[t] += u;
    __syncthreads();
  }
  int ex = (t == 0) ? 0 : sm[t-1];
#pragma unroll
  for(int i=0;i<SCH;i++){
    int idx = base+i;
    if(idx < NN) offs[idx] = ex + loc[i];
  }
  if(t == 0) offs[NN] = EE;
}

__global__ __launch_bounds__(256) void scatter_k(const int* __restrict__ src, const int* __restrict__ tgt,
                                                 const int* __restrict__ offs, int* __restrict__ cursor,
                                                 int* __restrict__ rank, int* __restrict__ tgt_s,
                                                 int* __restrict__ src_s){
  int e = blockIdx.x*blockDim.x + threadIdx.x;
  if(e < EE){
    int s = src[e];
    if((unsigned)s >= NN) s = 0;
    int pos = offs[s] + atomicAdd(&cursor[s], 1);
    rank[e] = pos;
    int t = tgt[e];
    if((unsigned)t >= NN) t = 0;
    tgt_s[pos] = t;
    src_s[pos] = s;
  }
}

// edge MLP v6: EPT=4 edges/thread amortizes wave-uniform LDS weight reads
__global__ __launch_bounds__(256, 2) void edge_mlp_q(const int* __restrict__ rank, const float* __restrict__ ea,
                                                  const float* __restrict__ w, const float* __restrict__ b,
                                                  const float* __restrict__ g, const float* __restrict__ beta,
                                                  const float* __restrict__ gat_a, const float* __restrict__ out_a,
                                                  __half* __restrict__ q8h, float* __restrict__ q_out,
                                                  unsigned* __restrict__ mx){
  __shared__ float P[64*20];
  __shared__ float smx[4][9];
  int tid = threadIdx.x;
  for(int idx=tid; idx<1280; idx+=256){
    int j = idx/20, c = idx - j*20;
    float v;
    if(c < 8)       v = w[c*64+j];
    else if(c == 8) v = b[j];
    else if(c == 9) v = g[j];
    else if(c ==10) v = beta[j];
    else if(c ==11) v = out_a[128+j];
    else            v = gat_a[(c-12)*192 + 128 + j];
    P[idx] = v;
  }
  __syncthreads();
  int base = blockIdx.x*(256*EPT) + tid;
  float4 ia[EPT], ib[EPT];
  bool  vl[EPT];
#pragma unroll
  for(int k=0;k<EPT;k++){
    int e = base + k*256;
    vl[k] = (e < EE);
    size_t es = vl[k] ? (size_t)e : 0;
    ia[k] = ((const float4*)ea)[es*2];
    ib[k] = ((const float4*)ea)[es*2+1];
  }
  float s1[EPT], s2[EPT];
#pragma unroll
  for(int k=0;k<EPT;k++){ s1[k]=0.f; s2[k]=0.f; }
#pragma unroll 4
  for(int j=0;j<64;j++){
    float4 w0 = *(const float4*)&P[j*20];
    float4 w1 = *(const float4*)&P[j*20+4];
    float4 c4 = *(const float4*)&P[j*20+8];
#pragma unroll
    for(int k=0;k<EPT;k++){
      float acc = c4.x;
      acc = fmaf(ia[k].x,w0.x, fmaf(ia[k].y,w0.y, fmaf(ia[k].z,w0.z, fmaf(ia[k].w,w0.w, acc))));
      acc = fmaf(ib[k].x,w1.x, fmaf(ib[k].y,w1.y, fmaf(ib[k].z,w1.z, fmaf(ib[k].w,w1.w, acc))));
      s1[k] += acc;
      s2[k] = fmaf(acc,acc,s2[k]);
    }
  }
  float mu[EPT], inv[EPT];
#pragma unroll
  for(int k=0;k<EPT;k++){
    mu[k]  = s1[k]*(1.0f/64.0f);
    float var = fmaxf(s2[k]*(1.0f/64.0f) - mu[k]*mu[k], 0.0f);
    inv[k] = rsqrtf(var + 1e-5f);
  }
  float qv[EPT][9];
#pragma unroll
  for(int k=0;k<EPT;k++)
#pragma unroll
    for(int r=0;r<9;r++) qv[k][r]=0.f;
#pragma unroll 4
  for(int j=0;j<64;j++){
    float4 w0 = *(const float4*)&P[j*20];
    float4 w1 = *(const float4*)&P[j*20+4];
    float4 c4 = *(const float4*)&P[j*20+8];   // ble,gle,bbe,a8
    float4 a0 = *(const float4*)&P[j*20+12];
    float4 a1 = *(const float4*)&P[j*20+16];
#pragma unroll
    for(int k=0;k<EPT;k++){
      float acc = c4.x;
      acc = fmaf(ia[k].x,w0.x, fmaf(ia[k].y,w0.y, fmaf(ia[k].z,w0.z, fmaf(ia[k].w,w0.w, acc))));
      acc = fmaf(ib[k].x,w1.x, fmaf(ib[k].y,w1.y, fmaf(ib[k].z,w1.z, fmaf(ib[k].w,w1.w, acc))));
      float yj = fmaxf(fmaf((acc - mu[k])*inv[k], c4.y, c4.z), 0.0f);
      qv[k][0]=fmaf(yj,a0.x,qv[k][0]); qv[k][1]=fmaf(yj,a0.y,qv[k][1]);
      qv[k][2]=fmaf(yj,a0.z,qv[k][2]); qv[k][3]=fmaf(yj,a0.w,qv[k][3]);
      qv[k][4]=fmaf(yj,a1.x,qv[k][4]); qv[k][5]=fmaf(yj,a1.y,qv[k][5]);
      qv[k][6]=fmaf(yj,a1.z,qv[k][6]); qv[k][7]=fmaf(yj,a1.w,qv[k][7]);
      qv[k][8]=fmaf(yj,c4.w,qv[k][8]);
    }
  }
  float mq[9];
#pragma unroll
  for(int r=0;r<9;r++) mq[r] = -3.0e38f;
#pragma unroll
  for(int k=0;k<EPT;k++){
    if(vl[k]){
      int e = base + k*256;
      int rk = rank[e];
      __half2 p01 = __floats2half2_rn(qv[k][0],qv[k][1]);
      __half2 p23 = __floats2half2_rn(qv[k][2],qv[k][3]);
      __half2 p45 = __floats2half2_rn(qv[k][4],qv[k][5]);
      __half2 p67 = __floats2half2_rn(qv[k][6],qv[k][7]);
      uint4 pk;
      pk.x = *(unsigned*)&p01; pk.y = *(unsigned*)&p23;
      pk.z = *(unsigned*)&p45; pk.w = *(unsigned*)&p67;
      *(uint4*)(q8h + (size_t)rk*8) = pk;
      q_out[rk] = qv[k][8];
#pragma unroll
      for(int r=0;r<9;r++) mq[r] = fmaxf(mq[r], qv[k][r]);
    }
  }
#pragma unroll
  for(int r=0;r<9;r++)
#pragma unroll
    for(int m=1;m<64;m<<=1) mq[r] = fmaxf(mq[r], __shfl_xor(mq[r],m,64));
  int wv = tid>>6, lane = tid&63;
  if(lane == 0){
#pragma unroll
    for(int r=0;r<9;r++) smx[wv][r] = mq[r];
  }
  __syncthreads();
  if(tid < 9){
    float v = fmaxf(fmaxf(smx[0][tid],smx[1][tid]), fmaxf(smx[2][tid],smx[3][tid]));
    atomicMax(&mx[tid], encf(v));
  }
}

__global__ __launch_bounds__(256) void maxp_k(const float* __restrict__ ps8, const float* __restrict__ pt8,
                                              unsigned* __restrict__ mx){
  float m[16];
#pragma unroll
  for(int r=0;r<16;r++) m[r] = -3.0e38f;
  for(int i = blockIdx.x*256 + threadIdx.x; i < NN; i += gridDim.x*256){
    float4 a = ((const float4*)ps8)[(size_t)i*2];
    float4 c = ((const float4*)ps8)[(size_t)i*2+1];
    float4 d = ((const float4*)pt8)[(size_t)i*2];
    float4 e = ((const float4*)pt8)[(size_t)i*2+1];
    m[0]=fmaxf(m[0],a.x); m[1]=fmaxf(m[1],a.y); m[2]=fmaxf(m[2],a.z); m[3]=fmaxf(m[3],a.w);
    m[4]=fmaxf(m[4],c.x); m[5]=fmaxf(m[5],c.y); m[6]=fmaxf(m[6],c.z); m[7]=fmaxf(m[7],c.w);
    m[8]=fmaxf(m[8],d.x); m[9]=fmaxf(m[9],d.y); m[10]=fmaxf(m[10],d.z); m[11]=fmaxf(m[11],d.w);
    m[12]=fmaxf(m[12],e.x); m[13]=fmaxf(m[13],e.y); m[14]=fmaxf(m[14],e.z); m[15]=fmaxf(m[15],e.w);
  }
#pragma unroll
  for(int r=0;r<16;r++)
#pragma unroll
    for(int msk=1;msk<64;msk<<=1) m[r] = fmaxf(m[r], __shfl_xor(m[r],msk,64));
  __shared__ float sm[4][16];
  int wv = threadIdx.x>>6, lane = threadIdx.x&63;
  if(lane == 0){
#pragma unroll
    for(int r=0;r<16;r++) sm[wv][r] = m[r];
  }
  __syncthreads();
  if(threadIdx.x < 16){
    int r = threadIdx.x;
    float v = fmaxf(fmaxf(sm[0][r],sm[1][r]), fmaxf(sm[2][r],sm[3][r]));
    atomicMax(&mx[16+r], encf(v));
  }
}

__global__ __launch_bounds__(256) void maxpo_k(const float* __restrict__ ps_o, const float* __restrict__ pt_o,
                                               unsigned* __restrict__ mx){
  float m0 = -3.0e38f, m1 = -3.0e38f;
  for(int i = blockIdx.x*256 + threadIdx.x; i < NN; i += gridDim.x*256){
    m0 = fmaxf(m0, ps_o[i]); m1 = fmaxf(m1, pt_o[i]);
  }
#pragma unroll
  for(int msk=1;msk<64;msk<<=1){ m0=fmaxf(m0,__shfl_xor(m0,msk,64)); m1=fmaxf(m1,__shfl_xor(m1,msk,64)); }
  __shared__ float sm[4][2];
  int wv = threadIdx.x>>6, lane = threadIdx.x&63;
  if(lane == 0){ sm[wv][0]=m0; sm[wv][1]=m1; }
  __syncthreads();
  if(threadIdx.x < 2){
    int r = threadIdx.x;
    float v = fmaxf(fmaxf(sm[0][r],sm[1][r]), fmaxf(sm[2][r],sm[3][r]));
    atomicMax(&mx[32+r], encf(v));
  }
}

// score: reads fp16 logits q8h, writes fp16 weights w8h
__global__ __launch_bounds__(256) void score_k(const int* __restrict__ src_s, const int* __restrict__ tgt_s,
                                               const float* __restrict__ ps8, const float* __restrict__ pt8,
                                               const unsigned* __restrict__ mx, const __half* __restrict__ q8h,
                                               __half* __restrict__ w8h){
  int i = blockIdx.x*256 + threadIdx.x;
  if(i >= EE) return;
  int s = src_s[i], t = tgt_s[i];
  uint4 rq = *(const uint4*)(q8h + (size_t)i*8);
  float2 q01 = __half22float2(*(const __half2*)&rq.x);
  float2 q23 = __half22float2(*(const __half2*)&rq.y);
  float2 q45 = __half22float2(*(const __half2*)&rq.z);
  float2 q67 = __half22float2(*(const __half2*)&rq.w);
  float4 sa = ((const float4*)ps8)[(size_t)s*2];
  float4 sb = ((const float4*)ps8)[(size_t)s*2+1];
  float4 ta = ((const float4*)pt8)[(size_t)t*2];
  float4 tb = ((const float4*)pt8)[(size_t)t*2+1];
  float sv[8] = {q01.x+sa.x+ta.x, q01.y+sa.y+ta.y, q23.x+sa.z+ta.z, q23.y+sa.w+ta.w,
                 q45.x+sb.x+tb.x, q45.y+sb.y+tb.y, q67.x+sb.z+tb.z, q67.y+sb.w+tb.w};
  float wv[8];
#pragma unroll
  for(int h=0;h<8;h++){
    float B = decf(mx[h]) + decf(mx[16+h]) + decf(mx[24+h]);
    float M = (B > 0.f) ? B : 0.01f*B;
    float x = sv[h];
    x = (x > 0.f) ? x : 0.01f*x;
    wv[h] = __expf(x - M);
  }
  __half2 p01 = __floats2half2_rn(wv[0],wv[1]);
  __half2 p23 = __floats2half2_rn(wv[2],wv[3]);
  __half2 p45 = __floats2half2_rn(wv[4],wv[5]);
  __half2 p67 = __floats2half2_rn(wv[6],wv[7]);
  uint4 pk;
  pk.x = *(unsigned*)&p01; pk.y = *(unsigned*)&p23;
  pk.z = *(unsigned*)&p45; pk.w = *(unsigned*)&p67;
  *(uint4*)(w8h + (size_t)i*8) = pk;
}

// R11: L2-windowed aggregation with KERNEL-BOUNDARY phase enforcement.
// agg_p0: edges with tgt<NHALF only (3.2MB gather window fits per-XCD L2);
// writes UNNORMALIZED fp16 num partial into pre + fp32 den into denp.
// agg_p1: edges with tgt>=NHALF; adds partial, normalizes, writes final pre.
__global__ __launch_bounds__(256) void agg_p0(const int* __restrict__ offs, const int* __restrict__ tgt_s,
    const __half* __restrict__ w8h, const __half* __restrict__ x, __half* __restrict__ pre,
    float* __restrict__ denp){
  int wid  = (blockIdx.x*blockDim.x + threadIdx.x) >> 6;
  int lane = threadIdx.x & 63;
  int quad = lane >> 4, l16 = lane & 15;
  int b  = offs[wid];
  int e2 = offs[wid+1];
  float  den[8];
  float4 num[8];
#pragma unroll
  for(int h=0;h<8;h++){ den[h] = 0.f; num[h] = make_float4(0.f,0.f,0.f,0.f); }
  for(int i=b+quad; i<e2; i+=4){
    int t = tgt_s[i];
    if(t < NHALF){
      uint4 rw = *(const uint4*)(w8h + (size_t)i*8);
      float2 w01 = __half22float2(*(const __half2*)&rw.x);
      float2 w23 = __half22float2(*(const __half2*)&rw.y);
      float2 w45 = __half22float2(*(const __half2*)&rw.z);
      float2 w67 = __half22float2(*(const __half2*)&rw.w);
      uint2 raw = *(const uint2*)(x + (size_t)t*64 + l16*4);
      float2 fa = __half22float2(*(const __half2*)&raw.x);
      float2 fb = __half22float2(*(const __half2*)&raw.y);
      float4 xv = make_float4(fa.x, fa.y, fb.x, fb.y);
      float wv[8] = {w01.x,w01.y,w23.x,w23.y, w45.x,w45.y,w67.x,w67.y};
#pragma unroll
      for(int h=0;h<8;h++){
        den[h]   += wv[h];
        num[h].x = fmaf(wv[h],xv.x,num[h].x); num[h].y = fmaf(wv[h],xv.y,num[h].y);
        num[h].z = fmaf(wv[h],xv.z,num[h].z); num[h].w = fmaf(wv[h],xv.w,num[h].w);
      }
    }
  }
#pragma unroll
  for(int h=0;h<8;h++){
    den[h]   += __shfl_xor(den[h],16,64);   den[h]   += __shfl_xor(den[h],32,64);
    num[h].x += __shfl_xor(num[h].x,16,64); num[h].x += __shfl_xor(num[h].x,32,64);
    num[h].y += __shfl_xor(num[h].y,16,64); num[h].y += __shfl_xor(num[h].y,32,64);
    num[h].z += __shfl_xor(num[h].z,16,64); num[h].z += __shfl_xor(num[h].z,32,64);
    num[h].w += __shfl_xor(num[h].w,16,64); num[h].w += __shfl_xor(num[h].w,32,64);
  }
  __half* dst = pre + (size_t)wid*512;
#pragma unroll
  for(int k=0;k<2;k++){
    int h = 2*quad + k;
    __half2 h0 = __floats2half2_rn(num[h].x, num[h].y);
    __half2 h1 = __floats2half2_rn(num[h].z, num[h].w);
    uint2 pk; pk.x = *(unsigned*)&h0; pk.y = *(unsigned*)&h1;
    *(uint2*)(dst + h*64 + l16*4) = pk;
    if(l16 == 0) denp[wid*8 + h] = den[h];
  }
}

__global__ __launch_bounds__(256) void agg_p1(const int* __restrict__ offs, const int* __restrict__ tgt_s,
    const __half* __restrict__ w8h, const __half* __restrict__ x, __half* __restrict__ pre,
    const float* __restrict__ denp){
  int wid  = (blockIdx.x*blockDim.x + threadIdx.x) >> 6;
  int lane = threadIdx.x & 63;
  int quad = lane >> 4, l16 = lane & 15;
  int b  = offs[wid];
  int e2 = offs[wid+1];
  float  den[8];
  float4 num[8];
#pragma unroll
  for(int h=0;h<8;h++){ den[h] = 0.f; num[h] = make_float4(0.f,0.f,0.f,0.f); }
  for(int i=b+quad; i<e2; i+=4){
    int t = tgt_s[i];
    if(t >= NHALF){
      uint4 rw = *(const uint4*)(w8h + (size_t)i*8);
      float2 w01 = __half22float2(*(const __half2*)&rw.x);
      float2 w23 = __half22float2(*(const __half2*)&rw.y);
      float2 w45 = __half22float2(*(const __half2*)&rw.z);
      float2 w67 = __half22float2(*(const __half2*)&rw.w);
      uint2 raw = *(const uint2*)(x + (size_t)t*64 + l16*4);
      float2 fa = __half22float2(*(const __half2*)&raw.x);
      float2 fb = __half22float2(*(const __half2*)&raw.y);
      float4 xv = make_float4(fa.x, fa.y, fb.x, fb.y);
      float wv[8] = {w01.x,w01.y,w23.x,w23.y, w45.x,w45.y,w67.x,w67.y};
#pragma unroll
      for(int h=0;h<8;h++){
        den[h]   += wv[h];
        num[h].x = fmaf(wv[h],xv.x,num[h].x); num[h].y = fmaf(wv[h],xv.y,num[h].y);
        num[h].z = fmaf(wv[h],xv.z,num[h].z); num[h].w = fmaf(wv[h],xv.w,num[h].w);
      }
    }
  }
#pragma unroll
  for(int h=0;h<8;h++){
    den[h]   += __shfl_xor(den[h],16,64);   den[h]   += __shfl_xor(den[h],32,64);
    num[h].x += __shfl_xor(num[h].x,16,64); num[h].x += __shfl_xor(num[h].x,32,64);
    num[h].y += __shfl_xor(num[h].y,16,64); num[h].y += __shfl_xor(num[h].y,32,64);
    num[h].z += __shfl_xor(num[h].z,16,64); num[h].z += __shfl_xor(num[h].z,32,64);
    num[h].w += __shfl_xor(num[h].w,16,64); num[h].w += __shfl_xor(num[h].w,32,64);
  }
  __half* dst = pre + (size_t)wid*512;
#pragma unroll
  for(int k=0;k<2;k++){
    int h = 2*quad + k;
    // add pass-0 partial (own-node read-before-write, wave-local)
    uint2 rp = *(const uint2*)(dst + h*64 + l16*4);
    float2 pa = __half22float2(*(const __half2*)&rp.x);
    float2 pb = __half22float2(*(const __half2*)&rp.y);
    float dtot = den[h] + denp[wid*8 + h];
    float nx = num[h].x + pa.x, ny = num[h].y + pa.y;
    float nz = num[h].z + pb.x, nw = num[h].w + pb.y;
    float invd = (dtot > 0.f) ? 1.0f/dtot : 0.f;
    __half2 h0 = __floats2half2_rn(nx*invd, ny*invd);
    __half2 h1 = __floats2half2_rn(nz*invd, nw*invd);
    uint2 pk; pk.x = *(unsigned*)&h0; pk.y = *(unsigned*)&h1;
    *(uint2*)(dst + h*64 + l16*4) = pk;
  }
}

// transform v7: MFMA, zero barriers, full N
__global__ __launch_bounds__(256) void transform_mfma(const __half* __restrict__ pre,
                                                      const __half* __restrict__ WT,
                                                      const __half* __restrict__ OT,
                                                      float* __restrict__ h2p){  // [2][NN][64]
  __shared__ __half zl[4*16*64];
  int tid = threadIdx.x;
  int w  = tid >> 6, l = tid & 63;
  int lr = l & 15, lg = l >> 4;
  int n0 = blockIdx.x * 64;
  int g  = blockIdx.y;
  h2p += (size_t)g * NN * 64;
  int gn  = n0 + w*16 + lr;
  int gnr = (gn < NN) ? gn : 0;
  __half* zw = zl + w*1024;
  f4a out[4];
#pragma unroll
  for(int i=0;i<4;i++){ out[i][0]=0.f; out[i][1]=0.f; out[i][2]=0.f; out[i][3]=0.f; }
#pragma unroll 1
  for(int hh=0; hh<4; hh++){
    int h = g*4 + hh;
    h8v a1_0 = *(const h8v*)(pre + (size_t)gnr*512 + h*64 + 0*32 + lg*8);
    h8v a1_1 = *(const h8v*)(pre + (size_t)gnr*512 + h*64 + 1*32 + lg*8);
    f4a zacc[4];
#pragma unroll
    for(int nt=0; nt<4; nt++){ zacc[nt][0]=0.f; zacc[nt][1]=0.f; zacc[nt][2]=0.f; zacc[nt][3]=0.f; }
    const __half* WTh = WT + (size_t)h*4096;
#pragma unroll
    for(int nt=0; nt<4; nt++){
      h8v b0 = *(const h8v*)(WTh + (nt*16 + lr)*64 + 0*32 + lg*8);
      h8v b1 = *(const h8v*)(WTh + (nt*16 + lr)*64 + 1*32 + lg*8);
      zacc[nt] = __builtin_amdgcn_mfma_f32_16x16x32_f16(a1_0, b0, zacc[nt], 0, 0, 0);
      zacc[nt] = __builtin_amdgcn_mfma_f32_16x16x32_f16(a1_1, b1, zacc[nt], 0, 0, 0);
    }
#pragma unroll
    for(int nt=0; nt<4; nt++){
#pragma unroll
      for(int r=0; r<4; r++){
        float v = zacc[nt][r];
        float z = (v > 0.f) ? v : expm1f(v);
        z = (z > 0.f) ? z : expm1f(z);
        int rho = lg*4 + r;
        int c   = nt*16 + lr;
        int pc  = (((c>>3) ^ (rho&7))<<3) | (c&7);
        zw[rho*64 + pc] = __float2half(z);
      }
    }
    const __half* OTh = OT + (size_t)h*4096;
#pragma unroll
    for(int ks=0; ks<2; ks++){
      int Gp = (lg + 4*ks) ^ (lr & 7);
      h8v a2 = *(const h8v*)(zw + lr*64 + Gp*8);
#pragma unroll
      for(int nt=0; nt<4; nt++){
        h8v b2 = *(const h8v*)(OTh + (nt*16 + lr)*64 + ks*32 + lg*8);
        out[nt] = __builtin_amdgcn_mfma_f32_16x16x32_f16(a2, b2, out[nt], 0, 0, 0);
      }
    }
  }
#pragma unroll
  for(int nt=0; nt<4; nt++){
#pragma unroll
    for(int r=0; r<4; r++){
      int grow = n0 + w*16 + lg*4 + r;
      if(grow < NN) h2p[(size_t)grow*64 + nt*16 + lr] = out[nt][r];
    }
  }
}

// finalize: h2f = p0+p1 stored fp16; ps_o/pt_o
__global__ __launch_bounds__(256) void finalize_po(const float* __restrict__ p0, const float* __restrict__ p1,
                                                   const float* __restrict__ out_a, __half* __restrict__ h2f,
                                                   float* __restrict__ ps_o, float* __restrict__ pt_o){
  int wid  = (blockIdx.x*blockDim.x + threadIdx.x) >> 6;
  int lane = threadIdx.x & 63;
  if(wid >= NN) return;
  float v = p0[(size_t)wid*64 + lane] + p1[(size_t)wid*64 + lane];
  float ps = wsum(v * out_a[lane]);
  float pt = wsum(v * out_a[64+lane]);
  if(lane == 0){ ps_o[wid] = ps; pt_o[wid] = pt; }
  h2f[(size_t)wid*64 + lane] = __float2half(v);
}

// R11: agg_out split the same way. Pass 0 writes fp32 num partial into dout
// (aliased scratch) + den into deno; pass 1 adds, normalizes, log_softmax.
__global__ __launch_bounds__(256) void aggo_p0(const int* __restrict__ offs, const int* __restrict__ tgt_s,
                                               const float* __restrict__ q_out, const float* __restrict__ ps_o,
                                               const float* __restrict__ pt_o, const unsigned* __restrict__ mx,
                                               const __half* __restrict__ h2f, float* __restrict__ doutp,
                                               float* __restrict__ deno){
  int wid  = (blockIdx.x*blockDim.x + threadIdx.x) >> 6;
  int lane = threadIdx.x & 63;
  if(wid >= NN) return;
  int quad = lane >> 4, l16 = lane & 15;
  int b  = offs[wid];
  int e2 = offs[wid+1];
  float B = decf(mx[8]) + decf(mx[32]) + decf(mx[33]);
  float M = (B > 0.f) ? B : 0.01f*B;
  float pso = ps_o[wid];
  float4 num = make_float4(0.f,0.f,0.f,0.f);
  float den = 0.f;
  for(int i=b+quad; i<e2; i+=4){
    int t = tgt_s[i];
    if(t < NHALF){
      float sv = q_out[i] + pso + pt_o[t];
      sv = (sv > 0.f) ? sv : 0.01f*sv;
      float w = __expf(sv - M);
      uint2 raw = *(const uint2*)(h2f + (size_t)t*64 + l16*4);
      float2 fa = __half22float2(*(const __half2*)&raw.x);
      float2 fb = __half22float2(*(const __half2*)&raw.y);
      den += w;
      num.x = fmaf(w,fa.x,num.x); num.y = fmaf(w,fa.y,num.y);
      num.z = fmaf(w,fb.x,num.z); num.w = fmaf(w,fb.y,num.w);
    }
  }
  den   += __shfl_xor(den,16,64);   den   += __shfl_xor(den,32,64);
  num.x += __shfl_xor(num.x,16,64); num.x += __shfl_xor(num.x,32,64);
  num.y += __shfl_xor(num.y,16,64); num.y += __shfl_xor(num.y,32,64);
  num.z += __shfl_xor(num.z,16,64); num.z += __shfl_xor(num.z,32,64);
  num.w += __shfl_xor(num.w,16,64); num.w += __shfl_xor(num.w,32,64);
  if(quad == 0){
    ((float4*)doutp)[(size_t)wid*16 + l16] = num;
    if(l16 == 0) deno[wid] = den;
  }
}

__global__ __launch_bounds__(256) void aggo_p1(const int* __restrict__ offs, const int* __restrict__ tgt_s,
                                               const float* __restrict__ q_out, const float* __restrict__ ps_o,
                                               const float* __restrict__ pt_o, const unsigned* __restrict__ mx,
                                               const __half* __restrict__ h2f, const float* __restrict__ deno,
                                               float* __restrict__ dout){
  int wid  = (blockIdx.x*blockDim.x + threadIdx.x) >> 6;
  int lane = threadIdx.x & 63;
  if(wid >= NN) return;
  int quad = lane >> 4, l16 = lane & 15;
  int b  = offs[wid];
  int e2 = offs[wid+1];
  float B = decf(mx[8]) + decf(mx[32]) + decf(mx[33]);
  float M = (B > 0.f) ? B : 0.01f*B;
  float pso = ps_o[wid];
  float4 num = make_float4(0.f,0.f,0.f,0.f);
  float den = 0.f;
  for(int i=b+quad; i<e2; i+=4){
    int t = tgt_s[i];
    if(t >= NHALF){
      float sv = q_out[i] + pso + pt_o[t];
      sv = (sv > 0.f) ? sv : 0.01f*sv;
      float w = __expf(sv - M);
      uint2 raw = *(const uint2*)(h2f + (size_t)t*64 + l16*4);
      float2 fa = __half22float2(*(const __half2*)&raw.x);
      float2 fb = __half22float2(*(const __half2*)&raw.y);
      den += w;
      num.x = fmaf(w,fa.x,num.x); num.y = fmaf(w,fa.y,num.y);
      num.z = fmaf(w,fb.x,num.z); num.w = fmaf(w,fb.y,num.w);
    }
  }
  den   += __shfl_xor(den,16,64);   den   += __shfl_xor(den,32,64);
  num.x += __shfl_xor(num.x,16,64); num.x += __shfl_xor(num.x,32,64);
  num.y += __shfl_xor(num.y,16,64); num.y += __shfl_xor(num.y,32,64);
  num.z += __shfl_xor(num.z,16,64); num.z += __shfl_xor(num.z,32,64);
  num.w += __shfl_xor(num.w,16,64); num.w += __shfl_xor(num.w,32,64);
  // add pass-0 partial (own-node read-before-write)
  if(quad == 0){
    float4 p = ((const float4*)dout)[(size_t)wid*16 + l16];
    num.x += p.x; num.y += p.y; num.z += p.z; num.w += p.w;
    den   += deno[wid];
  }
  float inv = (den > 0.f) ? 1.0f/den : 0.f;
  float z[4];
  float mloc = -3.0e38f;
#pragma unroll
  for(int k=0;k<4;k++){
    float hp = ((&num.x)[k]) * inv;
    z[k] = (hp > 0.f) ? hp : expm1f(hp);
    mloc = fmaxf(mloc, z[k]);
  }
#pragma unroll
  for(int msk=1; msk<16; msk<<=1) mloc = fmaxf(mloc, __shfl_xor(mloc,msk,64));
  float ssum = 0.f;
#pragma unroll
  for(int k=0;k<4;k++) ssum += __expf(z[k] - mloc);
#pragma unroll
  for(int msk=1; msk<16; msk<<=1) ssum += __shfl_xor(ssum,msk,64);
  float lse = mloc + logf(ssum);
  if(quad == 0){
    float4 o = make_float4(z[0]-lse, z[1]-lse, z[2]-lse, z[3]-lse);
    ((float4*)dout)[(size_t)wid*16 + l16] = o;
  }
}

extern "C" void kernel_launch(void* const* d_in, const int* in_sizes, int n_in,
                              void* d_out, int out_size, void* d_ws, size_t ws_size,
                              hipStream_t stream) {
  const float* X         = (const float*)d_in[0];
  const float* edge_attr = (const float*)d_in[1];
  const int*   edge_index= (const int*)d_in[2];
  const float* w_node    = (const float*)d_in[4];
  const float* b_node    = (const float*)d_in[5];
  const float* g_node    = (const float*)d_in[6];
  const float* beta_node = (const float*)d_in[7];
  const float* w_edge    = (const float*)d_in[8];
  const float* b_edge    = (const float*)d_in[9];
  const float* g_edge    = (const float*)d_in[10];
  const float* beta_edge = (const float*)d_in[11];
  const float* gat_W     = (const float*)d_in[12];
  const float* gat_a     = (const float*)d_in[13];
  const float* out_W     = (const float*)d_in[14];
  const float* out_a     = (const float*)d_in[15];
  float* dout = (float*)d_out;

  const int* src = edge_index;
  const int* tgt = edge_index + EE;

  char* base = (char*)d_ws;
  size_t off = 0;
  auto take = [&](size_t bytes)->char*{ char* p = base + off; off += (bytes + 31) & ~(size_t)31; return p; };
  int*      counts = (int*)     take((size_t)NN*4);
  int*      cursor = (int*)     take((size_t)NN*4);
  int*      offs   = (int*)     take((size_t)(NN+1)*4);
  unsigned* mx     = (unsigned*)take(64*4);
  float*    ps_o   = (float*)   take((size_t)NN*4);
  float*    pt_o   = (float*)   take((size_t)NN*4);
  float*    cdir   = (float*)   take(1024*4);
  int*      rank   = (int*)     take((size_t)EE*4);
  int*      tgt_s  = (int*)     take((size_t)EE*4);
  int*      src_s  = (int*)     take((size_t)EE*4);
  float*    ps8    = (float*)   take((size_t)NN*8*4);
  float*    pt8    = (float*)   take((size_t)NN*8*4);
  __half*   xh     = (__half*)  take((size_t)NN*64*2);
  __half*   h2fh   = (__half*)  take((size_t)NN*64*2);
  __half*   WT16   = (__half*)  take((size_t)8*4096*2);
  __half*   OT16   = (__half*)  take((size_t)8*4096*2);
  float*    h2p    = (float*)   take((size_t)2*NN*64*4);  // [2][NN][64] partials
  __half*   q8h    = (__half*)  take((size_t)EE*8*2);
  __half*   w8h    = (__half*)  take((size_t)EE*8*2);
  float*    q_out  = (float*)   take((size_t)EE*4);
  __half*   pre    = (__half*)  take((size_t)NN*512*2);
  float*    denp   = (float*)   take((size_t)NN*8*4);     // agg pass-0 den partial
  float*    deno   = (float*)   take((size_t)NN*4);       // agg_out pass-0 den partial

  const int NBLK_N  = (NN*64 + 255)/256;
  const int NBLK_E  = (EE + 255)/256;
  const int NBLK_EM = (EE + 256*EPT - 1)/(256*EPT);
  const int NBLK_S  = (NN + 255)/256;
  const int NBLK_A  = (NN + 3)/4;
  const int NBLK_T  = (NN + 63)/64;

  prep_k     <<<NBLK_S, 256, 0, stream>>>(counts, cursor, mx, gat_W, gat_a, out_W, out_a,
                                          cdir, WT16, OT16);
  node_hist_k<<<NBLK_N + NBLK_E, 256, 0, stream>>>(X, w_node, b_node, g_node, beta_node, cdir,
                                                   xh, ps8, pt8, src, counts);
  scan_k     <<<1,     1024, 0, stream>>>(counts, offs);
  scatter_k  <<<NBLK_E, 256, 0, stream>>>(src, tgt, offs, cursor, rank, tgt_s, src_s);
  edge_mlp_q <<<NBLK_EM,256, 0, stream>>>(rank, edge_attr, w_edge, b_edge, g_edge, beta_edge,
                                          gat_a, out_a, q8h, q_out, mx);
  maxp_k     <<<128,    256, 0, stream>>>(ps8, pt8, mx);
  score_k    <<<NBLK_E, 256, 0, stream>>>(src_s, tgt_s, ps8, pt8, mx, q8h, w8h);
  agg_p0     <<<NBLK_A, 256, 0, stream>>>(offs, tgt_s, w8h, xh, pre, denp);
  agg_p1     <<<NBLK_A, 256, 0, stream>>>(offs, tgt_s, w8h, xh, pre, denp);
  {
    dim3 tg((unsigned)NBLK_T, 2);
    transform_mfma<<<tg, 256, 0, stream>>>(pre, WT16, OT16, h2p);
  }
  finalize_po<<<NBLK_N, 256, 0, stream>>>(h2p, h2p + (size_t)NN*64, out_a, h2fh, ps_o, pt_o);
  maxpo_k    <<<128,  256, 0, stream>>>(ps_o, pt_o, mx);
  aggo_p0    <<<NBLK_N, 256, 0, stream>>>(offs, tgt_s, q_out, ps_o, pt_o, mx, h2fh, dout, deno);
  aggo_p1    <<<NBLK_N, 256, 0, stream>>>(offs, tgt_s, q_out, ps_o, pt_o, mx, h2fh, deno, dout);
}

// Round 12
// 629.065 us; speedup vs baseline: 1.3378x; 1.3378x over previous
//
#include <hip/hip_runtime.h>
#include <hip/hip_fp16.h>

#define NN 50000
#define EE 1000000
#define EPT 4

typedef _Float16 h8v __attribute__((ext_vector_type(8)));
typedef float    f4a __attribute__((ext_vector_type(4)));
typedef float    f4v __attribute__((ext_vector_type(4)));

__device__ __forceinline__ float wsum(float v){
#pragma unroll
  for(int m=1;m<64;m<<=1) v += __shfl_xor(v,m,64);
  return v;
}
__device__ __forceinline__ unsigned encf(float f){
  unsigned u = __float_as_uint(f);
  return (u & 0x80000000u) ? ~u : (u | 0x80000000u);
}
__device__ __forceinline__ float decf(unsigned u){
  u = (u & 0x80000000u) ? (u & 0x7fffffffu) : ~u;
  return __uint_as_float(u);
}

// prep: zero counts/cursor/mx (all blocks) + cvec + fp16 W/O transpose (blocks 0..7)
__global__ __launch_bounds__(256) void prep_k(int* counts, int* cursor, unsigned* mx,
                                              const float* __restrict__ gat_W, const float* __restrict__ gat_a,
                                              const float* __restrict__ out_W, const float* __restrict__ out_a,
                                              float* __restrict__ cdir, __half* __restrict__ WT,
                                              __half* __restrict__ OT){
  int i = blockIdx.x*256 + threadIdx.x;
  if(i < NN){ counts[i] = 0; cursor[i] = 0; }
  if(i < 64) mx[i] = 0u;
  if(blockIdx.x < 8){
    int h = blockIdx.x, tid = threadIdx.x;
    if(tid < 64){
      const float* W = gat_W + (size_t)h*4096;
      const float* a = gat_a + (size_t)h*192;
      float cs = 0.f, ct = 0.f;
#pragma unroll
      for(int j=0;j<64;j++){ float wv = W[tid*64+j]; cs += wv*a[j]; ct += wv*a[64+j]; }
      cdir[h*64 + tid]       = cs;
      cdir[512 + h*64 + tid] = ct;
    }
    for(int idx = tid; idx < 4096; idx += 256){
      int j = idx >> 6, k = idx & 63;
      WT[(size_t)h*4096 + k*64 + j] = __float2half(gat_W[(size_t)h*4096 + j*64 + k]);
      OT[(size_t)h*4096 + k*64 + j] = __float2half(out_W[(size_t)h*4096 + j*64 + k]);
    }
  }
}

// node MLP (blocks < NB_N) + edge histogram (remaining blocks)
__global__ __launch_bounds__(256) void node_hist_k(const float* __restrict__ X, const float* __restrict__ w,
                                                   const float* __restrict__ b, const float* __restrict__ g,
                                                   const float* __restrict__ beta, const float* __restrict__ cdir,
                                                   __half* __restrict__ x, float* __restrict__ ps8,
                                                   float* __restrict__ pt8,
                                                   const int* __restrict__ src, int* __restrict__ counts){
  const int NB_N = (NN*64 + 255)/256;
  if(blockIdx.x >= NB_N){
    int e = (blockIdx.x - NB_N)*256 + threadIdx.x;
    if(e < EE){
      int s = src[e];
      if((unsigned)s >= NN) s = 0;
      atomicAdd(&counts[s], 1);
    }
    return;
  }
  int wid  = (blockIdx.x*256 + threadIdx.x) >> 6;
  int lane = threadIdx.x & 63;
  if(wid >= NN) return;
  float acc = b[lane];
#pragma unroll
  for(int k=0;k<16;k++) acc += X[wid*16+k] * w[k*64+lane];
  float mu  = wsum(acc) * (1.0f/64.0f);
  float d   = acc - mu;
  float var = wsum(d*d) * (1.0f/64.0f);
  float y   = d * rsqrtf(var + 1e-5f) * g[lane] + beta[lane];
  float xv  = fmaxf(y, 0.0f);
  x[(size_t)wid*64 + lane] = __float2half(xv);
#pragma unroll 1
  for(int h=0;h<8;h++){
    float a = wsum(xv * cdir[h*64+lane]);
    float c = wsum(xv * cdir[512 + h*64+lane]);
    if(lane == 0){ ps8[wid*8+h] = a; pt8[wid*8+h] = c; }
  }
}

// parallel 3-kernel scan (R9's single-block scan_k serialized ~25us on one CU)
__global__ __launch_bounds__(256) void scan1_k(const int* __restrict__ counts, int* __restrict__ bsum){
  int i = blockIdx.x*256 + threadIdx.x;
  int v = (i < NN) ? counts[i] : 0;
  int s = v;
#pragma unroll
  for(int m=1;m<64;m<<=1) s += __shfl_xor(s,m,64);
  __shared__ int sm[4];
  if((threadIdx.x & 63) == 0) sm[threadIdx.x>>6] = s;
  __syncthreads();
  if(threadIdx.x == 0) bsum[blockIdx.x] = sm[0]+sm[1]+sm[2]+sm[3];
}

__global__ __launch_bounds__(256) void scan2_k(const int* __restrict__ bsum, int* __restrict__ bpre,
                                               int* __restrict__ offs){
  const int NB = (NN + 255)/256;
  int t = threadIdx.x;
  __shared__ int sm[256];
  int v = (t < NB) ? bsum[t] : 0;
  sm[t] = v; __syncthreads();
  for(int off=1; off<256; off<<=1){
    int u = (t >= off) ? sm[t-off] : 0;
    __syncthreads();
    sm[t] += u;
    __syncthreads();
  }
  if(t < NB) bpre[t] = sm[t] - v;
  if(t == 0) offs[NN] = EE;
}

__global__ __launch_bounds__(256) void scan3_k(const int* __restrict__ counts, const int* __restrict__ bpre,
                                               int* __restrict__ offs){
  int i = blockIdx.x*256 + threadIdx.x;
  int t = threadIdx.x;
  __shared__ int sm[256];
  int v = (i < NN) ? counts[i] : 0;
  sm[t] = v; __syncthreads();
  for(int off=1; off<256; off<<=1){
    int u = (t >= off) ? sm[t-off] : 0;
    __syncthreads();
    sm[t] += u;
    __syncthreads();
  }
  if(i < NN) offs[i] = bpre[blockIdx.x] + sm[t] - v;
}

__global__ __launch_bounds__(256) void scatter_k(const int* __restrict__ src, const int* __restrict__ tgt,
                                                 const int* __restrict__ offs, int* __restrict__ cursor,
                                                 int* __restrict__ rank, int* __restrict__ tgt_s,
                                                 int* __restrict__ src_s){
  int e = blockIdx.x*blockDim.x + threadIdx.x;
  if(e < EE){
    int s = src[e];
    if((unsigned)s >= NN) s = 0;
    int pos = offs[s] + atomicAdd(&cursor[s], 1);
    rank[e] = pos;
    int t = tgt[e];
    if((unsigned)t >= NN) t = 0;
    tgt_s[pos] = t;
    src_s[pos] = s;
  }
}

// edge MLP v6: EPT=4 edges/thread amortizes wave-uniform LDS weight reads
__global__ __launch_bounds__(256, 2) void edge_mlp_q(const int* __restrict__ rank, const float* __restrict__ ea,
                                                  const float* __restrict__ w, const float* __restrict__ b,
                                                  const float* __restrict__ g, const float* __restrict__ beta,
                                                  const float* __restrict__ gat_a, const float* __restrict__ out_a,
                                                  __half* __restrict__ q8h, float* __restrict__ q_out,
                                                  unsigned* __restrict__ mx){
  __shared__ float P[64*20];
  __shared__ float smx[4][9];
  int tid = threadIdx.x;
  for(int idx=tid; idx<1280; idx+=256){
    int j = idx/20, c = idx - j*20;
    float v;
    if(c < 8)       v = w[c*64+j];
    else if(c == 8) v = b[j];
    else if(c == 9) v = g[j];
    else if(c ==10) v = beta[j];
    else if(c ==11) v = out_a[128+j];
    else            v = gat_a[(c-12)*192 + 128 + j];
    P[idx] = v;
  }
  __syncthreads();
  int base = blockIdx.x*(256*EPT) + tid;
  float4 ia[EPT], ib[EPT];
  bool  vl[EPT];
#pragma unroll
  for(int k=0;k<EPT;k++){
    int e = base + k*256;
    vl[k] = (e < EE);
    size_t es = vl[k] ? (size_t)e : 0;
    ia[k] = ((const float4*)ea)[es*2];
    ib[k] = ((const float4*)ea)[es*2+1];
  }
  float s1[EPT], s2[EPT];
#pragma unroll
  for(int k=0;k<EPT;k++){ s1[k]=0.f; s2[k]=0.f; }
#pragma unroll 4
  for(int j=0;j<64;j++){
    float4 w0 = *(const float4*)&P[j*20];
    float4 w1 = *(const float4*)&P[j*20+4];
    float4 c4 = *(const float4*)&P[j*20+8];
#pragma unroll
    for(int k=0;k<EPT;k++){
      float acc = c4.x;
      acc = fmaf(ia[k].x,w0.x, fmaf(ia[k].y,w0.y, fmaf(ia[k].z,w0.z, fmaf(ia[k].w,w0.w, acc))));
      acc = fmaf(ib[k].x,w1.x, fmaf(ib[k].y,w1.y, fmaf(ib[k].z,w1.z, fmaf(ib[k].w,w1.w, acc))));
      s1[k] += acc;
      s2[k] = fmaf(acc,acc,s2[k]);
    }
  }
  float mu[EPT], inv[EPT];
#pragma unroll
  for(int k=0;k<EPT;k++){
    mu[k]  = s1[k]*(1.0f/64.0f);
    float var = fmaxf(s2[k]*(1.0f/64.0f) - mu[k]*mu[k], 0.0f);
    inv[k] = rsqrtf(var + 1e-5f);
  }
  float qv[EPT][9];
#pragma unroll
  for(int k=0;k<EPT;k++)
#pragma unroll
    for(int r=0;r<9;r++) qv[k][r]=0.f;
#pragma unroll 4
  for(int j=0;j<64;j++){
    float4 w0 = *(const float4*)&P[j*20];
    float4 w1 = *(const float4*)&P[j*20+4];
    float4 c4 = *(const float4*)&P[j*20+8];   // ble,gle,bbe,a8
    float4 a0 = *(const float4*)&P[j*20+12];
    float4 a1 = *(const float4*)&P[j*20+16];
#pragma unroll
    for(int k=0;k<EPT;k++){
      float acc = c4.x;
      acc = fmaf(ia[k].x,w0.x, fmaf(ia[k].y,w0.y, fmaf(ia[k].z,w0.z, fmaf(ia[k].w,w0.w, acc))));
      acc = fmaf(ib[k].x,w1.x, fmaf(ib[k].y,w1.y, fmaf(ib[k].z,w1.z, fmaf(ib[k].w,w1.w, acc))));
      float yj = fmaxf(fmaf((acc - mu[k])*inv[k], c4.y, c4.z), 0.0f);
      qv[k][0]=fmaf(yj,a0.x,qv[k][0]); qv[k][1]=fmaf(yj,a0.y,qv[k][1]);
      qv[k][2]=fmaf(yj,a0.z,qv[k][2]); qv[k][3]=fmaf(yj,a0.w,qv[k][3]);
      qv[k][4]=fmaf(yj,a1.x,qv[k][4]); qv[k][5]=fmaf(yj,a1.y,qv[k][5]);
      qv[k][6]=fmaf(yj,a1.z,qv[k][6]); qv[k][7]=fmaf(yj,a1.w,qv[k][7]);
      qv[k][8]=fmaf(yj,c4.w,qv[k][8]);
    }
  }
  float mq[9];
#pragma unroll
  for(int r=0;r<9;r++) mq[r] = -3.0e38f;
#pragma unroll
  for(int k=0;k<EPT;k++){
    if(vl[k]){
      int e = base + k*256;
      int rk = rank[e];
      __half2 p01 = __floats2half2_rn(qv[k][0],qv[k][1]);
      __half2 p23 = __floats2half2_rn(qv[k][2],qv[k][3]);
      __half2 p45 = __floats2half2_rn(qv[k][4],qv[k][5]);
      __half2 p67 = __floats2half2_rn(qv[k][6],qv[k][7]);
      uint4 pk;
      pk.x = *(unsigned*)&p01; pk.y = *(unsigned*)&p23;
      pk.z = *(unsigned*)&p45; pk.w = *(unsigned*)&p67;
      *(uint4*)(q8h + (size_t)rk*8) = pk;
      q_out[rk] = qv[k][8];
#pragma unroll
      for(int r=0;r<9;r++) mq[r] = fmaxf(mq[r], qv[k][r]);
    }
  }
#pragma unroll
  for(int r=0;r<9;r++)
#pragma unroll
    for(int m=1;m<64;m<<=1) mq[r] = fmaxf(mq[r], __shfl_xor(mq[r],m,64));
  int wv = tid>>6, lane = tid&63;
  if(lane == 0){
#pragma unroll
    for(int r=0;r<9;r++) smx[wv][r] = mq[r];
  }
  __syncthreads();
  if(tid < 9){
    float v = fmaxf(fmaxf(smx[0][tid],smx[1][tid]), fmaxf(smx[2][tid],smx[3][tid]));
    atomicMax(&mx[tid], encf(v));
  }
}

__global__ __launch_bounds__(256) void maxp_k(const float* __restrict__ ps8, const float* __restrict__ pt8,
                                              unsigned* __restrict__ mx){
  float m[16];
#pragma unroll
  for(int r=0;r<16;r++) m[r] = -3.0e38f;
  for(int i = blockIdx.x*256 + threadIdx.x; i < NN; i += gridDim.x*256){
    float4 a = ((const float4*)ps8)[(size_t)i*2];
    float4 c = ((const float4*)ps8)[(size_t)i*2+1];
    float4 d = ((const float4*)pt8)[(size_t)i*2];
    float4 e = ((const float4*)pt8)[(size_t)i*2+1];
    m[0]=fmaxf(m[0],a.x); m[1]=fmaxf(m[1],a.y); m[2]=fmaxf(m[2],a.z); m[3]=fmaxf(m[3],a.w);
    m[4]=fmaxf(m[4],c.x); m[5]=fmaxf(m[5],c.y); m[6]=fmaxf(m[6],c.z); m[7]=fmaxf(m[7],c.w);
    m[8]=fmaxf(m[8],d.x); m[9]=fmaxf(m[9],d.y); m[10]=fmaxf(m[10],d.z); m[11]=fmaxf(m[11],d.w);
    m[12]=fmaxf(m[12],e.x); m[13]=fmaxf(m[13],e.y); m[14]=fmaxf(m[14],e.z); m[15]=fmaxf(m[15],e.w);
  }
#pragma unroll
  for(int r=0;r<16;r++)
#pragma unroll
    for(int msk=1;msk<64;msk<<=1) m[r] = fmaxf(m[r], __shfl_xor(m[r],msk,64));
  __shared__ float sm[4][16];
  int wv = threadIdx.x>>6, lane = threadIdx.x&63;
  if(lane == 0){
#pragma unroll
    for(int r=0;r<16;r++) sm[wv][r] = m[r];
  }
  __syncthreads();
  if(threadIdx.x < 16){
    int r = threadIdx.x;
    float v = fmaxf(fmaxf(sm[0][r],sm[1][r]), fmaxf(sm[2][r],sm[3][r]));
    atomicMax(&mx[16+r], encf(v));
  }
}

__global__ __launch_bounds__(256) void maxpo_k(const float* __restrict__ ps_o, const float* __restrict__ pt_o,
                                               unsigned* __restrict__ mx){
  float m0 = -3.0e38f, m1 = -3.0e38f;
  for(int i = blockIdx.x*256 + threadIdx.x; i < NN; i += gridDim.x*256){
    m0 = fmaxf(m0, ps_o[i]); m1 = fmaxf(m1, pt_o[i]);
  }
#pragma unroll
  for(int msk=1;msk<64;msk<<=1){ m0=fmaxf(m0,__shfl_xor(m0,msk,64)); m1=fmaxf(m1,__shfl_xor(m1,msk,64)); }
  __shared__ float sm[4][2];
  int wv = threadIdx.x>>6, lane = threadIdx.x&63;
  if(lane == 0){ sm[wv][0]=m0; sm[wv][1]=m1; }
  __syncthreads();
  if(threadIdx.x < 2){
    int r = threadIdx.x;
    float v = fmaxf(fmaxf(sm[0][r],sm[1][r]), fmaxf(sm[2][r],sm[3][r]));
    atomicMax(&mx[32+r], encf(v));
  }
}

// score: reads fp16 logits q8h, writes fp16 weights w8h
__global__ __launch_bounds__(256) void score_k(const int* __restrict__ src_s, const int* __restrict__ tgt_s,
                                               const float* __restrict__ ps8, const float* __restrict__ pt8,
                                               const unsigned* __restrict__ mx, const __half* __restrict__ q8h,
                                               __half* __restrict__ w8h){
  int i = blockIdx.x*256 + threadIdx.x;
  if(i >= EE) return;
  int s = src_s[i], t = tgt_s[i];
  uint4 rq = *(const uint4*)(q8h + (size_t)i*8);
  float2 q01 = __half22float2(*(const __half2*)&rq.x);
  float2 q23 = __half22float2(*(const __half2*)&rq.y);
  float2 q45 = __half22float2(*(const __half2*)&rq.z);
  float2 q67 = __half22float2(*(const __half2*)&rq.w);
  float4 sa = ((const float4*)ps8)[(size_t)s*2];
  float4 sb = ((const float4*)ps8)[(size_t)s*2+1];
  float4 ta = ((const float4*)pt8)[(size_t)t*2];
  float4 tb = ((const float4*)pt8)[(size_t)t*2+1];
  float sv[8] = {q01.x+sa.x+ta.x, q01.y+sa.y+ta.y, q23.x+sa.z+ta.z, q23.y+sa.w+ta.w,
                 q45.x+sb.x+tb.x, q45.y+sb.y+tb.y, q67.x+sb.z+tb.z, q67.y+sb.w+tb.w};
  float wv[8];
#pragma unroll
  for(int h=0;h<8;h++){
    float B = decf(mx[h]) + decf(mx[16+h]) + decf(mx[24+h]);
    float M = (B > 0.f) ? B : 0.01f*B;
    float x = sv[h];
    x = (x > 0.f) ? x : 0.01f*x;
    wv[h] = __expf(x - M);
  }
  __half2 p01 = __floats2half2_rn(wv[0],wv[1]);
  __half2 p23 = __floats2half2_rn(wv[2],wv[3]);
  __half2 p45 = __floats2half2_rn(wv[4],wv[5]);
  __half2 p67 = __floats2half2_rn(wv[6],wv[7]);
  uint4 pk;
  pk.x = *(unsigned*)&p01; pk.y = *(unsigned*)&p23;
  pk.z = *(unsigned*)&p45; pk.w = *(unsigned*)&p67;
  *(uint4*)(w8h + (size_t)i*8) = pk;
}

// aggregation (R9-validated single-pass, full N): plain loads; fp16 x gather;
// fp16 pre store. L2-windowing refuted (R10/R11: WRITE component invariant).
__global__ __launch_bounds__(256) void agg_k(const int* __restrict__ offs, const int* __restrict__ tgt_s,
    const __half* __restrict__ w8h, const __half* __restrict__ x, __half* __restrict__ pre){
  int wid  = (blockIdx.x*blockDim.x + threadIdx.x) >> 6;
  int lane = threadIdx.x & 63;
  int quad = lane >> 4, l16 = lane & 15;
  int b  = offs[wid];
  int e2 = offs[wid+1];
  float  den[8];
  float4 num[8];
#pragma unroll
  for(int h=0;h<8;h++){ den[h] = 0.f; num[h] = make_float4(0.f,0.f,0.f,0.f); }
  for(int i=b+quad; i<e2; i+=4){
    int t = tgt_s[i];
    uint4 rw = *(const uint4*)(w8h + (size_t)i*8);
    float2 w01 = __half22float2(*(const __half2*)&rw.x);
    float2 w23 = __half22float2(*(const __half2*)&rw.y);
    float2 w45 = __half22float2(*(const __half2*)&rw.z);
    float2 w67 = __half22float2(*(const __half2*)&rw.w);
    uint2 raw = *(const uint2*)(x + (size_t)t*64 + l16*4);
    float2 fa = __half22float2(*(const __half2*)&raw.x);
    float2 fb = __half22float2(*(const __half2*)&raw.y);
    float4 xv = make_float4(fa.x, fa.y, fb.x, fb.y);
    float wv[8] = {w01.x,w01.y,w23.x,w23.y, w45.x,w45.y,w67.x,w67.y};
#pragma unroll
    for(int h=0;h<8;h++){
      den[h]   += wv[h];
      num[h].x = fmaf(wv[h],xv.x,num[h].x); num[h].y = fmaf(wv[h],xv.y,num[h].y);
      num[h].z = fmaf(wv[h],xv.z,num[h].z); num[h].w = fmaf(wv[h],xv.w,num[h].w);
    }
  }
#pragma unroll
  for(int h=0;h<8;h++){
    den[h]   += __shfl_xor(den[h],16,64);   den[h]   += __shfl_xor(den[h],32,64);
    num[h].x += __shfl_xor(num[h].x,16,64); num[h].x += __shfl_xor(num[h].x,32,64);
    num[h].y += __shfl_xor(num[h].y,16,64); num[h].y += __shfl_xor(num[h].y,32,64);
    num[h].z += __shfl_xor(num[h].z,16,64); num[h].z += __shfl_xor(num[h].z,32,64);
    num[h].w += __shfl_xor(num[h].w,16,64); num[h].w += __shfl_xor(num[h].w,32,64);
  }
  __half* dst = pre + (size_t)wid*512;
#pragma unroll
  for(int k=0;k<2;k++){
    int h = 2*quad + k;
    float invd = (den[h] > 0.f) ? 1.0f/den[h] : 0.f;
    __half2 h0 = __floats2half2_rn(num[h].x*invd, num[h].y*invd);
    __half2 h1 = __floats2half2_rn(num[h].z*invd, num[h].w*invd);
    uint2 pk; pk.x = *(unsigned*)&h0; pk.y = *(unsigned*)&h1;
    *(uint2*)(dst + h*64 + l16*4) = pk;
  }
}

// transform v7: MFMA, zero barriers, full N
__global__ __launch_bounds__(256) void transform_mfma(const __half* __restrict__ pre,
                                                      const __half* __restrict__ WT,
                                                      const __half* __restrict__ OT,
                                                      float* __restrict__ h2p){  // [2][NN][64]
  __shared__ __half zl[4*16*64];
  int tid = threadIdx.x;
  int w  = tid >> 6, l = tid & 63;
  int lr = l & 15, lg = l >> 4;
  int n0 = blockIdx.x * 64;
  int g  = blockIdx.y;
  h2p += (size_t)g * NN * 64;
  int gn  = n0 + w*16 + lr;
  int gnr = (gn < NN) ? gn : 0;
  __half* zw = zl + w*1024;
  f4a out[4];
#pragma unroll
  for(int i=0;i<4;i++){ out[i][0]=0.f; out[i][1]=0.f; out[i][2]=0.f; out[i][3]=0.f; }
#pragma unroll 1
  for(int hh=0; hh<4; hh++){
    int h = g*4 + hh;
    h8v a1_0 = *(const h8v*)(pre + (size_t)gnr*512 + h*64 + 0*32 + lg*8);
    h8v a1_1 = *(const h8v*)(pre + (size_t)gnr*512 + h*64 + 1*32 + lg*8);
    f4a zacc[4];
#pragma unroll
    for(int nt=0; nt<4; nt++){ zacc[nt][0]=0.f; zacc[nt][1]=0.f; zacc[nt][2]=0.f; zacc[nt][3]=0.f; }
    const __half* WTh = WT + (size_t)h*4096;
#pragma unroll
    for(int nt=0; nt<4; nt++){
      h8v b0 = *(const h8v*)(WTh + (nt*16 + lr)*64 + 0*32 + lg*8);
      h8v b1 = *(const h8v*)(WTh + (nt*16 + lr)*64 + 1*32 + lg*8);
      zacc[nt] = __builtin_amdgcn_mfma_f32_16x16x32_f16(a1_0, b0, zacc[nt], 0, 0, 0);
      zacc[nt] = __builtin_amdgcn_mfma_f32_16x16x32_f16(a1_1, b1, zacc[nt], 0, 0, 0);
    }
#pragma unroll
    for(int nt=0; nt<4; nt++){
#pragma unroll
      for(int r=0; r<4; r++){
        float v = zacc[nt][r];
        float z = (v > 0.f) ? v : expm1f(v);
        z = (z > 0.f) ? z : expm1f(z);
        int rho = lg*4 + r;
        int c   = nt*16 + lr;
        int pc  = (((c>>3) ^ (rho&7))<<3) | (c&7);
        zw[rho*64 + pc] = __float2half(z);
      }
    }
    const __half* OTh = OT + (size_t)h*4096;
#pragma unroll
    for(int ks=0; ks<2; ks++){
      int Gp = (lg + 4*ks) ^ (lr & 7);
      h8v a2 = *(const h8v*)(zw + lr*64 + Gp*8);
#pragma unroll
      for(int nt=0; nt<4; nt++){
        h8v b2 = *(const h8v*)(OTh + (nt*16 + lr)*64 + ks*32 + lg*8);
        out[nt] = __builtin_amdgcn_mfma_f32_16x16x32_f16(a2, b2, out[nt], 0, 0, 0);
      }
    }
  }
#pragma unroll
  for(int nt=0; nt<4; nt++){
#pragma unroll
    for(int r=0; r<4; r++){
      int grow = n0 + w*16 + lg*4 + r;
      if(grow < NN) h2p[(size_t)grow*64 + nt*16 + lr] = out[nt][r];
    }
  }
}

// finalize: h2f = p0+p1 stored fp16; ps_o/pt_o
__global__ __launch_bounds__(256) void finalize_po(const float* __restrict__ p0, const float* __restrict__ p1,
                                                   const float* __restrict__ out_a, __half* __restrict__ h2f,
                                                   float* __restrict__ ps_o, float* __restrict__ pt_o){
  int wid  = (blockIdx.x*blockDim.x + threadIdx.x) >> 6;
  int lane = threadIdx.x & 63;
  if(wid >= NN) return;
  float v = p0[(size_t)wid*64 + lane] + p1[(size_t)wid*64 + lane];
  float ps = wsum(v * out_a[lane]);
  float pt = wsum(v * out_a[64+lane]);
  if(lane == 0){ ps_o[wid] = ps; pt_o[wid] = pt; }
  h2f[(size_t)wid*64 + lane] = __float2half(v);
}

// output aggregation (R9-validated): fused score_out + log_softmax; NT dout.
__global__ __launch_bounds__(256) void agg_out(const int* __restrict__ offs, const int* __restrict__ tgt_s,
                                               const float* __restrict__ q_out, const float* __restrict__ ps_o,
                                               const float* __restrict__ pt_o, const unsigned* __restrict__ mx,
                                               const __half* __restrict__ h2f, float* __restrict__ dout){
  int wid  = (blockIdx.x*blockDim.x + threadIdx.x) >> 6;
  int lane = threadIdx.x & 63;
  if(wid >= NN) return;
  int quad = lane >> 4, l16 = lane & 15;
  int b  = offs[wid];
  int e2 = offs[wid+1];
  float B = decf(mx[8]) + decf(mx[32]) + decf(mx[33]);
  float M = (B > 0.f) ? B : 0.01f*B;
  float pso = ps_o[wid];
  float4 num = make_float4(0.f,0.f,0.f,0.f);
  float den = 0.f;
  for(int i=b+quad; i<e2; i+=4){
    int t = tgt_s[i];
    float sv = q_out[i] + pso + pt_o[t];
    sv = (sv > 0.f) ? sv : 0.01f*sv;
    float w = __expf(sv - M);
    uint2 raw = *(const uint2*)(h2f + (size_t)t*64 + l16*4);
    float2 fa = __half22float2(*(const __half2*)&raw.x);
    float2 fb = __half22float2(*(const __half2*)&raw.y);
    den += w;
    num.x = fmaf(w,fa.x,num.x); num.y = fmaf(w,fa.y,num.y);
    num.z = fmaf(w,fb.x,num.z); num.w = fmaf(w,fb.y,num.w);
  }
  den   += __shfl_xor(den,16,64);   den   += __shfl_xor(den,32,64);
  num.x += __shfl_xor(num.x,16,64); num.x += __shfl_xor(num.x,32,64);
  num.y += __shfl_xor(num.y,16,64); num.y += __shfl_xor(num.y,32,64);
  num.z += __shfl_xor(num.z,16,64); num.z += __shfl_xor(num.z,32,64);
  num.w += __shfl_xor(num.w,16,64); num.w += __shfl_xor(num.w,32,64);
  float inv = (den > 0.f) ? 1.0f/den : 0.f;
  float z[4];
  float mloc = -3.0e38f;
#pragma unroll
  for(int k=0;k<4;k++){
    float hp = ((&num.x)[k]) * inv;
    z[k] = (hp > 0.f) ? hp : expm1f(hp);
    mloc = fmaxf(mloc, z[k]);
  }
#pragma unroll
  for(int msk=1; msk<16; msk<<=1) mloc = fmaxf(mloc, __shfl_xor(mloc,msk,64));
  float ssum = 0.f;
#pragma unroll
  for(int k=0;k<4;k++) ssum += __expf(z[k] - mloc);
#pragma unroll
  for(int msk=1; msk<16; msk<<=1) ssum += __shfl_xor(ssum,msk,64);
  float lse = mloc + logf(ssum);
  if(quad == 0){
    f4v o; o.x = z[0]-lse; o.y = z[1]-lse; o.z = z[2]-lse; o.w = z[3]-lse;
    __builtin_nontemporal_store(o, (f4v*)(dout + (size_t)wid*64 + l16*4));
  }
}

extern "C" void kernel_launch(void* const* d_in, const int* in_sizes, int n_in,
                              void* d_out, int out_size, void* d_ws, size_t ws_size,
                              hipStream_t stream) {
  const float* X         = (const float*)d_in[0];
  const float* edge_attr = (const float*)d_in[1];
  const int*   edge_index= (const int*)d_in[2];
  const float* w_node    = (const float*)d_in[4];
  const float* b_node    = (const float*)d_in[5];
  const float* g_node    = (const float*)d_in[6];
  const float* beta_node = (const float*)d_in[7];
  const float* w_edge    = (const float*)d_in[8];
  const float* b_edge    = (const float*)d_in[9];
  const float* g_edge    = (const float*)d_in[10];
  const float* beta_edge = (const float*)d_in[11];
  const float* gat_W     = (const float*)d_in[12];
  const float* gat_a     = (const float*)d_in[13];
  const float* out_W     = (const float*)d_in[14];
  const float* out_a     = (const float*)d_in[15];
  float* dout = (float*)d_out;

  const int* src = edge_index;
  const int* tgt = edge_index + EE;

  char* base = (char*)d_ws;
  size_t off = 0;
  auto take = [&](size_t bytes)->char*{ char* p = base + off; off += (bytes + 31) & ~(size_t)31; return p; };
  int*      counts = (int*)     take((size_t)NN*4);
  int*      cursor = (int*)     take((size_t)NN*4);
  int*      offs   = (int*)     take((size_t)(NN+1)*4);
  int*      bsum   = (int*)     take(256*4);
  int*      bpre   = (int*)     take(256*4);
  unsigned* mx     = (unsigned*)take(64*4);
  float*    ps_o   = (float*)   take((size_t)NN*4);
  float*    pt_o   = (float*)   take((size_t)NN*4);
  float*    cdir   = (float*)   take(1024*4);
  int*      rank   = (int*)     take((size_t)EE*4);
  int*      tgt_s  = (int*)     take((size_t)EE*4);
  int*      src_s  = (int*)     take((size_t)EE*4);
  float*    ps8    = (float*)   take((size_t)NN*8*4);
  float*    pt8    = (float*)   take((size_t)NN*8*4);
  __half*   xh     = (__half*)  take((size_t)NN*64*2);
  __half*   h2fh   = (__half*)  take((size_t)NN*64*2);
  __half*   WT16   = (__half*)  take((size_t)8*4096*2);
  __half*   OT16   = (__half*)  take((size_t)8*4096*2);
  float*    h2p    = (float*)   take((size_t)2*NN*64*4);  // [2][NN][64] partials
  __half*   q8h    = (__half*)  take((size_t)EE*8*2);
  __half*   w8h    = (__half*)  take((size_t)EE*8*2);
  float*    q_out  = (float*)   take((size_t)EE*4);
  __half*   pre    = (__half*)  take((size_t)NN*512*2);   // full N

  const int NBLK_N  = (NN*64 + 255)/256;
  const int NBLK_E  = (EE + 255)/256;
  const int NBLK_EM = (EE + 256*EPT - 1)/(256*EPT);
  const int NBLK_S  = (NN + 255)/256;
  const int NBLK_A  = (NN + 3)/4;
  const int NBLK_T  = (NN + 63)/64;

  prep_k     <<<NBLK_S, 256, 0, stream>>>(counts, cursor, mx, gat_W, gat_a, out_W, out_a,
                                          cdir, WT16, OT16);
  node_hist_k<<<NBLK_N + NBLK_E, 256, 0, stream>>>(X, w_node, b_node, g_node, beta_node, cdir,
                                                   xh, ps8, pt8, src, counts);
  scan1_k    <<<NBLK_S, 256, 0, stream>>>(counts, bsum);
  scan2_k    <<<1,      256, 0, stream>>>(bsum, bpre, offs);
  scan3_k    <<<NBLK_S, 256, 0, stream>>>(counts, bpre, offs);
  scatter_k  <<<NBLK_E, 256, 0, stream>>>(src, tgt, offs, cursor, rank, tgt_s, src_s);
  edge_mlp_q <<<NBLK_EM,256, 0, stream>>>(rank, edge_attr, w_edge, b_edge, g_edge, beta_edge,
                                          gat_a, out_a, q8h, q_out, mx);
  maxp_k     <<<128,    256, 0, stream>>>(ps8, pt8, mx);
  score_k    <<<NBLK_E, 256, 0, stream>>>(src_s, tgt_s, ps8, pt8, mx, q8h, w8h);
  agg_k      <<<NBLK_A, 256, 0, stream>>>(offs, tgt_s, w8h, xh, pre);
  {
    dim3 tg((unsigned)NBLK_T, 2);
    transform_mfma<<<tg, 256, 0, stream>>>(pre, WT16, OT16, h2p);
  }
  finalize_po<<<NBLK_N, 256, 0, stream>>>(h2p, h2p + (size_t)NN*64, out_a, h2fh, ps_o, pt_o);
  maxpo_k    <<<128,  256, 0, stream>>>(ps_o, pt_o, mx);
  agg_out    <<<NBLK_N,256, 0, stream>>>(offs, tgt_s, q_out, ps_o, pt_o, mx, h2fh, dout);
}